// Round 10
// baseline (325.473 us; speedup 1.0000x reference)
//
#include <hip/hip_runtime.h>

typedef _Float16 f16;
typedef __attribute__((ext_vector_type(4))) _Float16 f16x4;
typedef __attribute__((ext_vector_type(8))) _Float16 f16x8;
typedef __attribute__((ext_vector_type(4))) float f32x4;

#define B_ 8192
#define D_ 784
#define H_ 1024
#define L_ 128
#define T_ 10
#define KP1 896          // D padded to multiple of 64
#define NPH 896          // head N padded to 896
#define MAXTILES (B_/128 + T_)   // 74 (128-row tile map)
#define PADROWS 256

// ctrl int indices
#define C_COUNT 0
#define C_CURS 16
#define C_OFFS 32
#define C_NTILES 49
#define C_TTASK 64
#define C_TROW 160

__global__ void k_init(int* ctrl) {
    if (threadIdx.x < 64) ctrl[threadIdx.x] = 0;
}

__global__ void k_count(const int* __restrict__ task, int* __restrict__ ctrl) {
    int b = blockIdx.x * 256 + threadIdx.x;
    if (b < B_) atomicAdd(&ctrl[C_COUNT + task[b]], 1);
}

__global__ void k_scan(int* ctrl) {
    if (threadIdx.x == 0 && blockIdx.x == 0) {
        int off = 0;
        ctrl[C_OFFS] = 0;
        for (int t = 0; t < T_; ++t) { off += ctrl[C_COUNT + t]; ctrl[C_OFFS + t + 1] = off; }
        int nt = 0;
        for (int t = 0; t < T_; ++t)
            for (int r = ctrl[C_OFFS + t]; r < ctrl[C_OFFS + t + 1]; r += 128) {
                ctrl[C_TTASK + nt] = t; ctrl[C_TROW + nt] = r; ++nt;
            }
        ctrl[C_NTILES] = nt;
    }
}

__global__ void k_scatter(const int* __restrict__ task, int* __restrict__ ctrl, int* __restrict__ perm) {
    int b = blockIdx.x * 256 + threadIdx.x;
    if (b >= B_) return;
    int t = task[b];
    int i = ctrl[C_OFFS + t] + atomicAdd(&ctrl[C_CURS + t], 1);
    perm[i] = b;
}

__global__ void k_gather_x(const float* __restrict__ x, const int* __restrict__ perm, f16* __restrict__ Xp) {
    int i = blockIdx.x;
    int r = perm[i];
    int c = threadIdx.x * 4;
    if (c >= KP1) return;
    f16x4 o = (f16x4){0, 0, 0, 0};
    if (c < D_) {
        float4 v = *(const float4*)(x + (long)r * D_ + c);
        o[0] = (f16)v.x; o[1] = (f16)v.y; o[2] = (f16)v.z; o[3] = (f16)v.w;
    }
    *(f16x4*)(Xp + (long)i * KP1 + c) = o;
}

// ---------------------------------------------------------------------------
// Fused transpose-convert, register-pipelined persistent blocks.
// Next job's global loads are issued BEFORE processing the current tile and
// stay in flight across the LDS phases (raw lgkmcnt barriers, never vmcnt(0)).
// ---------------------------------------------------------------------------
struct ConvSeg { const float* src; f16* dst; int K, N, Kp, Np, ntx, nty, base; };
struct ConvArgs { ConvSeg s[6]; };

__global__ __launch_bounds__(256)
void k_convAll(ConvArgs args, int njobs) {
    __shared__ float tile[64][65];
    int tid = threadIdx.x;
    int rr = tid >> 4, cc = (tid & 15) * 4;   // read-phase coords
    int nr = tid >> 3, kk = (tid & 7) * 8;    // write-phase coords

    auto decode = [&](int job, int& si, int& t, int& k0, int& n0) {
        si = 0;
#pragma unroll
        for (int i = 1; i < 6; ++i) si = (job >= args.s[i].base) ? i : si;
        int rel = job - args.s[si].base;
        int perT = args.s[si].ntx * args.s[si].nty;
        t = rel / perT; rel -= t * perT;
        int ty = rel / args.s[si].ntx;
        int tx = rel - ty * args.s[si].ntx;
        k0 = tx * 64; n0 = ty * 64;
    };
    auto loadregs = [&](int job, float4* v) {
        int si, t, k0, n0; decode(job, si, t, k0, n0);
        const ConvSeg& sg = args.s[si];
        const float* s = sg.src + (long)t * sg.K * sg.N;
#pragma unroll
        for (int p = 0; p < 4; ++p) {
            int k = k0 + rr + p * 16;
            int gn = n0 + cc;
            float4 vv = {0.f, 0.f, 0.f, 0.f};
            if (k < sg.K) {
                const float* sp = s + (long)k * sg.N + gn;
                if (gn + 3 < sg.N) vv = *(const float4*)sp;
                else {
                    if (gn + 0 < sg.N) vv.x = sp[0];
                    if (gn + 1 < sg.N) vv.y = sp[1];
                    if (gn + 2 < sg.N) vv.z = sp[2];
                    if (gn + 3 < sg.N) vv.w = sp[3];
                }
            }
            v[p] = vv;
        }
    };

    int job = blockIdx.x;
    if (job >= njobs) return;
    float4 v[4];
    loadregs(job, v);
    while (true) {
        int nxt = job + gridDim.x;
        bool have = (nxt < njobs);
        float4 w[4];
        if (have) loadregs(nxt, w);   // in flight across the phases below

        int si, t, k0, n0; decode(job, si, t, k0, n0);
        const ConvSeg& sg = args.s[si];
        f16* d = sg.dst + (long)t * sg.Np * sg.Kp;
#pragma unroll
        for (int p = 0; p < 4; ++p) {
            tile[rr + p * 16][cc + 0] = v[p].x;
            tile[rr + p * 16][cc + 1] = v[p].y;
            tile[rr + p * 16][cc + 2] = v[p].z;
            tile[rr + p * 16][cc + 3] = v[p].w;
        }
        asm volatile("s_waitcnt lgkmcnt(0)" ::: "memory");
        __builtin_amdgcn_s_barrier();
#pragma unroll
        for (int p = 0; p < 2; ++p) {
            int n = n0 + nr + p * 32;
            f16x8 o;
#pragma unroll
            for (int u = 0; u < 8; ++u) o[u] = (f16)tile[kk + u][nr + p * 32];
            if (n < sg.Np) *(f16x8*)(d + (long)n * sg.Kp + k0 + kk) = o;
        }
        if (!have) break;
        asm volatile("s_waitcnt lgkmcnt(0)" ::: "memory");
        __builtin_amdgcn_s_barrier();
#pragma unroll
        for (int p = 0; p < 4; ++p) v[p] = w[p];
        job = nxt;
    }
}

// z = mu + exp(ls) * eps  (permuted rows)
__global__ void k_z(const float* __restrict__ mu, const float* __restrict__ ls,
                    const float* __restrict__ eps, const int* __restrict__ perm,
                    f16* __restrict__ Z) {
    long gid = (long)blockIdx.x * 256 + threadIdx.x;
    int i = (int)(gid >> 7), c = (int)(gid & 127);
    int r = perm[i];
    float m = mu[(long)r * L_ + c];
    float l = ls[(long)r * L_ + c];
    Z[(long)i * L_ + c] = (f16)(m + __expf(l) * eps[(long)r * L_ + c]);
}

// ---------------------------------------------------------------------------
// 128x128 GEMM, BK=64, 2-deep double-buffer with counted vmcnt (r6 protocol
// at 64KB LDS -> 2 blocks/CU), persistent job loop, 4 waves (2Mx2N).
// Per iter: vmcnt(8|0) -> s_barrier -> compute -> lgkmcnt(0)+s_barrier ->
// STAGE(i+2). Loads get a full iteration to land; no __syncthreads in loop
// (its vmcnt(0) drain kills the prefetch - r2 lesson).
// Ledger: prologue stages t0,t1 (16 in flight). Top of iter i: drain to 8
// (t_i landed, t_{i+1} flying) or 0 at the tail. NI is even for all layers.
// ---------------------------------------------------------------------------
template <int EPI, bool GROUPED>
__global__ __launch_bounds__(256, 2)
void k_gemmD(const f16* __restrict__ A,
             const f16* __restrict__ W, long wstride,
             const float* __restrict__ bias, int bstride,
             int K, int N, int ntn,
             f16* __restrict__ outF16, float* __restrict__ o0, float* __restrict__ o1,
             const int* __restrict__ ctrl, const int* __restrict__ perm) {
    __shared__ char lds[65536];   // 2 buffers x (A 16KB + B 16KB)
    int tid = threadIdx.x, lane = tid & 63;
    int wave = tid >> 6, wm = wave >> 1, wn = wave & 1;

    // bijective XCD swizzle (m204)
    int nwg = gridDim.x, orig = blockIdx.x;
    int qq = nwg >> 3, rr8 = nwg & 7, xcd = orig & 7, idx = orig >> 3;
    int wgid = (xcd < rr8 ? xcd * (qq + 1) : rr8 * (qq + 1) + (xcd - rr8) * qq) + idx;

    // staging: thread g covers (row g>>3 in a 32-row chunk, LDS slot g&7);
    // global 16B-chunk = (g&7) ^ (row&7)  (inverse swizzle).
    int rowc = tid >> 3;
    long srcElem = (long)rowc * K + (((tid & 7) ^ (rowc & 7)) << 3);
    int dstOff = wave << 10;   // wave-uniform; HW adds lane*16

    // read addressing: byte = row*128 + (slot^(lane&7))*16, slot = ks*4+(lane>>4)
    int slot0 = ((lane >> 4) ^ (lane & 7)) << 4;
    int aoff = (wm * 64 + (lane & 15)) * 128 + slot0;
    int boff = 16384 + (wn * 64 + (lane & 15)) * 128 + slot0;

    int mtiles = GROUPED ? ctrl[C_NTILES] : (B_ / 128);
    int njobs = mtiles * ntn;
    int NI = K >> 6;

    for (int job = wgid; job < njobs; job += nwg) {
        int tm = job / ntn, tn = job - tm * ntn;
        int t, row0, mrows;
        if (GROUPED) {
            t = ctrl[C_TTASK + tm];
            row0 = ctrl[C_TROW + tm];
            mrows = min(128, ctrl[C_OFFS + t + 1] - row0);
        } else {
            t = 0; row0 = tm * 128; mrows = 128;
        }
        const f16* Wt = W + (long)t * wstride;
        const float* bt = bias + (long)t * bstride;
        int n0 = tn * 128;
        const f16* Abase = A + (long)row0 * K + srcElem;
        const f16* Bbase = Wt + (long)n0 * K + srcElem;

        auto STAGE = [&](int buf, int kt) {
            const f16* a = Abase + kt * 64;
            const f16* b = Bbase + kt * 64;
            char* base = lds + buf * 32768;
#pragma unroll
            for (int c = 0; c < 4; ++c) {
                __builtin_amdgcn_global_load_lds(
                    (const __attribute__((address_space(1))) unsigned int*)(a + (long)c * 32 * K),
                    (__attribute__((address_space(3))) unsigned int*)(base + c * 4096 + dstOff), 16, 0, 0);
                __builtin_amdgcn_global_load_lds(
                    (const __attribute__((address_space(1))) unsigned int*)(b + (long)c * 32 * K),
                    (__attribute__((address_space(3))) unsigned int*)(base + 16384 + c * 4096 + dstOff), 16, 0, 0);
            }
        };

        f32x4 acc[4][4];
#pragma unroll
        for (int i = 0; i < 4; ++i)
#pragma unroll
            for (int j = 0; j < 4; ++j) acc[i][j] = (f32x4){0.f, 0.f, 0.f, 0.f};

        STAGE(0, 0);
        if (NI > 1) STAGE(1, 1);
        for (int i = 0; i < NI; ++i) {
            if (i + 1 < NI) asm volatile("s_waitcnt vmcnt(8)" ::: "memory");
            else            asm volatile("s_waitcnt vmcnt(0)" ::: "memory");
            __builtin_amdgcn_s_barrier();

            const char* base = lds + (i & 1) * 32768;
#pragma unroll
            for (int ks = 0; ks < 2; ++ks) {
                int xo = ((slot0 ^ (ks * 64)) - slot0);
                f16x8 af[4], bf[4];
#pragma unroll
                for (int mi = 0; mi < 4; ++mi)
                    af[mi] = *(const f16x8*)(base + aoff + mi * 2048 + xo);
#pragma unroll
                for (int nj = 0; nj < 4; ++nj)
                    bf[nj] = *(const f16x8*)(base + boff + nj * 2048 + xo);
#pragma unroll
                for (int mi = 0; mi < 4; ++mi)
#pragma unroll
                    for (int nj = 0; nj < 4; ++nj)
                        acc[mi][nj] = __builtin_amdgcn_mfma_f32_16x16x32_f16(af[mi], bf[nj], acc[mi][nj], 0, 0, 0);
            }

            asm volatile("s_waitcnt lgkmcnt(0)" ::: "memory");
            __builtin_amdgcn_s_barrier();
            if (i + 2 < NI) STAGE(i & 1, i + 2);
        }

        // epilogue (no LDS use; buffers already safe for next job's STAGE)
        int cq = lane >> 4, cr = lane & 15;
#pragma unroll
        for (int mi = 0; mi < 4; ++mi) {
#pragma unroll
            for (int nj = 0; nj < 4; ++nj) {
#pragma unroll
                for (int reg = 0; reg < 4; ++reg) {
                    int rl = wm * 64 + mi * 16 + cq * 4 + reg;
                    if (rl >= mrows) continue;
                    int gcol = n0 + wn * 64 + nj * 16 + cr;
                    if (gcol >= N) continue;
                    float v = acc[mi][nj][reg] + bt[gcol];
                    int grow = row0 + rl;
                    if (EPI == 0) {
                        outF16[(long)grow * H_ + gcol] = (f16)(v > 0.f ? v : 0.f);
                    } else if (EPI == 1) {
                        int r = perm[grow];
                        if (gcol < L_) o0[(long)r * L_ + gcol] = v;
                        else o1[(long)r * L_ + (gcol - L_)] = v;
                    } else {
                        o0[(long)perm[grow] * D_ + gcol] = 1.f / (1.f + __expf(-v));
                    }
                }
            }
        }
    }
}

extern "C" void kernel_launch(void* const* d_in, const int* in_sizes, int n_in,
                              void* d_out, int out_size, void* d_ws, size_t ws_size,
                              hipStream_t stream) {
    const float* x   = (const float*)d_in[0];
    const float* eps = (const float*)d_in[1];
    const float* eW1 = (const float*)d_in[2];
    const float* eb1 = (const float*)d_in[3];
    const float* eW2 = (const float*)d_in[4];
    const float* eb2 = (const float*)d_in[5];
    const float* eW3 = (const float*)d_in[6];
    const float* eb3 = (const float*)d_in[7];
    const float* dW1 = (const float*)d_in[8];
    const float* db1 = (const float*)d_in[9];
    const float* dW2 = (const float*)d_in[10];
    const float* db2 = (const float*)d_in[11];
    const float* hW  = (const float*)d_in[12];
    const float* hb  = (const float*)d_in[13];
    const int* task  = (const int*)d_in[14];

    float* out = (float*)d_out;
    float* recon = out;
    float* mu = out + (size_t)B_ * D_;
    float* ls = mu + (size_t)B_ * L_;

    char* w = (char*)d_ws;
    size_t o = 0;
    auto alloc = [&](size_t bytes) -> char* {
        char* p = w + o;
        o = (o + bytes + 255) & ~(size_t)255;
        return p;
    };
    int* ctrl  = (int*)alloc(4096);
    int* perm  = (int*)alloc((size_t)B_ * 4);
    f16* Xp    = (f16*)alloc((size_t)(B_ + PADROWS) * KP1 * 2);
    f16* H1    = (f16*)alloc((size_t)(B_ + PADROWS) * H_ * 2);
    f16* H2    = (f16*)alloc((size_t)(B_ + PADROWS) * H_ * 2);
    f16* Z     = (f16*)alloc((size_t)(B_ + PADROWS) * L_ * 2);
    f16* Wt1   = (f16*)alloc((size_t)T_ * H_ * KP1 * 2);
    f16* Wt2   = (f16*)alloc((size_t)T_ * H_ * H_ * 2);
    f16* Wt3   = (f16*)alloc((size_t)T_ * 256 * H_ * 2);
    f16* WtD1  = (f16*)alloc((size_t)H_ * L_ * 2);
    f16* WtD2  = (f16*)alloc((size_t)H_ * H_ * 2);
    f16* WtH   = (f16*)alloc((size_t)T_ * NPH * H_ * 2);
    if (o > ws_size) return;

    k_init<<<1, 64, 0, stream>>>(ctrl);
    k_count<<<B_ / 256, 256, 0, stream>>>(task, ctrl);
    k_scan<<<1, 1, 0, stream>>>(ctrl);
    k_scatter<<<B_ / 256, 256, 0, stream>>>(task, ctrl, perm);
    k_gather_x<<<B_, 256, 0, stream>>>(x, perm, Xp);

    ConvArgs ca;
    int base = 0;
    auto seg = [&](const float* s, f16* d, int K, int N, int Kp, int Np, int T) {
        ConvSeg sg; sg.src = s; sg.dst = d; sg.K = K; sg.N = N; sg.Kp = Kp; sg.Np = Np;
        sg.ntx = Kp / 64; sg.nty = Np / 64; sg.base = base;
        base += sg.ntx * sg.nty * T;
        return sg;
    };
    ca.s[0] = seg(eW1, Wt1, D_, H_, KP1, H_, T_);
    ca.s[1] = seg(eW2, Wt2, H_, H_, H_, H_, T_);
    ca.s[2] = seg(eW3, Wt3, H_, 256, H_, 256, T_);
    ca.s[3] = seg(dW1, WtD1, L_, H_, L_, H_, 1);
    ca.s[4] = seg(dW2, WtD2, H_, H_, H_, H_, 1);
    ca.s[5] = seg(hW, WtH, H_, D_, H_, NPH, T_);
    k_convAll<<<1024, 256, 0, stream>>>(ca, base);

    // encoder layer 1: Xp(K=896) @ Wt1 -> relu -> H1
    k_gemmD<0, true><<<512, 256, 0, stream>>>(
        Xp, Wt1, (long)H_ * KP1, eb1, H_, KP1, H_, 8, H1, nullptr, nullptr, ctrl, perm);
    // encoder layer 2: H1 @ Wt2 -> relu -> H2
    k_gemmD<0, true><<<512, 256, 0, stream>>>(
        H1, Wt2, (long)H_ * H_, eb2, H_, H_, H_, 8, H2, nullptr, nullptr, ctrl, perm);
    // encoder layer 3: H2 @ Wt3 -> mu/ls perm-scatter
    k_gemmD<1, true><<<148, 256, 0, stream>>>(
        H2, Wt3, (long)256 * H_, eb3, 256, H_, 256, 2, nullptr, mu, ls, ctrl, perm);
    // z = mu + exp(ls)*eps
    k_z<<<(B_ * L_) / 256, 256, 0, stream>>>(mu, ls, eps, perm, Z);
    // decoder layer 1: Z(K=128) @ WtD1 -> relu -> H1
    k_gemmD<0, false><<<512, 256, 0, stream>>>(
        Z, WtD1, 0, db1, 0, L_, H_, 8, H1, nullptr, nullptr, ctrl, perm);
    // decoder layer 2: H1 @ WtD2 -> relu -> H2
    k_gemmD<0, false><<<512, 256, 0, stream>>>(
        H1, WtD2, 0, db2, 0, H_, H_, 8, H2, nullptr, nullptr, ctrl, perm);
    // head: H2 @ WtH -> sigmoid -> recon (perm-scatter fp32)
    k_gemmD<2, true><<<512, 256, 0, stream>>>(
        H2, WtH, (long)NPH * H_, hb, D_, H_, D_, 7, nullptr, recon, nullptr, ctrl, perm);
}

// Round 11
// 276.860 us; speedup vs baseline: 1.1756x; 1.1756x over previous
//
#include <hip/hip_runtime.h>

typedef _Float16 f16;
typedef __attribute__((ext_vector_type(4))) _Float16 f16x4;
typedef __attribute__((ext_vector_type(8))) _Float16 f16x8;
typedef __attribute__((ext_vector_type(4))) float f32x4;

#define B_ 8192
#define D_ 784
#define H_ 1024
#define L_ 128
#define T_ 10
#define KP1 896          // D padded to multiple of 64
#define NPH 896          // head N padded to 896
#define MAXTILES (B_/128 + T_)   // 74 (128-row tile map)
#define PADROWS 256

// ctrl int indices
#define C_COUNT 0
#define C_CURS 16
#define C_OFFS 32
#define C_NTILES 49
#define C_TTASK 64
#define C_TROW 160

__global__ void k_init(int* ctrl) {
    if (threadIdx.x < 64) ctrl[threadIdx.x] = 0;
}

__global__ void k_count(const int* __restrict__ task, int* __restrict__ ctrl) {
    int b = blockIdx.x * 256 + threadIdx.x;
    if (b < B_) atomicAdd(&ctrl[C_COUNT + task[b]], 1);
}

__global__ void k_scan(int* ctrl) {
    if (threadIdx.x == 0 && blockIdx.x == 0) {
        int off = 0;
        ctrl[C_OFFS] = 0;
        for (int t = 0; t < T_; ++t) { off += ctrl[C_COUNT + t]; ctrl[C_OFFS + t + 1] = off; }
        int nt = 0;
        for (int t = 0; t < T_; ++t)
            for (int r = ctrl[C_OFFS + t]; r < ctrl[C_OFFS + t + 1]; r += 128) {
                ctrl[C_TTASK + nt] = t; ctrl[C_TROW + nt] = r; ++nt;
            }
        ctrl[C_NTILES] = nt;
    }
}

__global__ void k_scatter(const int* __restrict__ task, int* __restrict__ ctrl, int* __restrict__ perm) {
    int b = blockIdx.x * 256 + threadIdx.x;
    if (b >= B_) return;
    int t = task[b];
    int i = ctrl[C_OFFS + t] + atomicAdd(&ctrl[C_CURS + t], 1);
    perm[i] = b;
}

__global__ void k_gather_x(const float* __restrict__ x, const int* __restrict__ perm, f16* __restrict__ Xp) {
    int i = blockIdx.x;
    int r = perm[i];
    int c = threadIdx.x * 4;
    if (c >= KP1) return;
    f16x4 o = (f16x4){0, 0, 0, 0};
    if (c < D_) {
        float4 v = *(const float4*)(x + (long)r * D_ + c);
        o[0] = (f16)v.x; o[1] = (f16)v.y; o[2] = (f16)v.z; o[3] = (f16)v.w;
    }
    *(f16x4*)(Xp + (long)i * KP1 + c) = o;
}

// ---------------------------------------------------------------------------
// Fused transpose-convert for ALL weight tensors (r9 version: 1 job/block).
// ---------------------------------------------------------------------------
struct ConvSeg { const float* src; f16* dst; int K, N, Kp, Np, ntx, nty, base; };
struct ConvArgs { ConvSeg s[6]; };

__global__ void k_convAll(ConvArgs args) {
    __shared__ float tile[64][65];
    int bid = blockIdx.x;
    int si = 0;
#pragma unroll
    for (int i = 1; i < 6; ++i) si = (bid >= args.s[i].base) ? i : si;
    ConvSeg sg = args.s[si];
    int rel = bid - sg.base;
    int perT = sg.ntx * sg.nty;
    int t = rel / perT; rel -= t * perT;
    int ty = rel / sg.ntx;
    int tx = rel - ty * sg.ntx;
    int k0 = tx * 64, n0 = ty * 64;
    const float* s = sg.src + (long)t * sg.K * sg.N;
    f16* d = sg.dst + (long)t * sg.Np * sg.Kp;
    int tid = threadIdx.x;

    int rr = tid >> 4, cc = (tid & 15) * 4;
#pragma unroll
    for (int p = 0; p < 4; ++p) {
        int k = k0 + rr + p * 16;
        int gn = n0 + cc;
        float4 v = {0.f, 0.f, 0.f, 0.f};
        if (k < sg.K) {
            const float* sp = s + (long)k * sg.N + gn;
            if (gn + 3 < sg.N) v = *(const float4*)sp;
            else {
                if (gn + 0 < sg.N) v.x = sp[0];
                if (gn + 1 < sg.N) v.y = sp[1];
                if (gn + 2 < sg.N) v.z = sp[2];
                if (gn + 3 < sg.N) v.w = sp[3];
            }
        }
        tile[rr + p * 16][cc + 0] = v.x;
        tile[rr + p * 16][cc + 1] = v.y;
        tile[rr + p * 16][cc + 2] = v.z;
        tile[rr + p * 16][cc + 3] = v.w;
    }
    __syncthreads();
    int nr = tid >> 3, kk = (tid & 7) * 8;
#pragma unroll
    for (int p = 0; p < 2; ++p) {
        int n = n0 + nr + p * 32;
        f16x8 o;
#pragma unroll
        for (int u = 0; u < 8; ++u) o[u] = (f16)tile[kk + u][nr + p * 32];
        if (n < sg.Np) *(f16x8*)(d + (long)n * sg.Kp + k0 + kk) = o;
    }
}

// z = mu + exp(ls) * eps  (permuted rows)
__global__ void k_z(const float* __restrict__ mu, const float* __restrict__ ls,
                    const float* __restrict__ eps, const int* __restrict__ perm,
                    f16* __restrict__ Z) {
    long gid = (long)blockIdx.x * 256 + threadIdx.x;
    int i = (int)(gid >> 7), c = (int)(gid & 127);
    int r = perm[i];
    float m = mu[(long)r * L_ + c];
    float l = ls[(long)r * L_ + c];
    Z[(long)i * L_ + c] = (f16)(m + __expf(l) * eps[(long)r * L_ + c]);
}

// ---------------------------------------------------------------------------
// 128M x 64N GEMM, BK=64, SINGLE 24KB LDS buffer, 4 waves (2Mx2N),
// per-wave 64x32 = acc[4][2] of 16x16x32 f16 MFMA.
// Same m97-faithful sync-sync loop as r9 (best so far) but HALF-width N-tiles
// -> 2x grid (1024-1184 blocks = 4.6/CU) -> ~4 co-resident blocks/CU for
// inter-block latency hiding (m114). LDS 24KB, regs ~128 -> not binding.
// ---------------------------------------------------------------------------
template <int EPI, bool GROUPED>
__global__ __launch_bounds__(256, 4)
void k_gemmD(const f16* __restrict__ A,
             const f16* __restrict__ W, long wstride,
             const float* __restrict__ bias, int bstride,
             int K, int N, int ntn,
             f16* __restrict__ outF16, float* __restrict__ o0, float* __restrict__ o1,
             const int* __restrict__ ctrl, const int* __restrict__ perm) {
    __shared__ char lds[24576];   // A [128][64]f16 @0 (16KB), B [64][64] @16384 (8KB)
    int tid = threadIdx.x, lane = tid & 63;
    int wave = tid >> 6, wm = wave >> 1, wn = wave & 1;

    // bijective XCD swizzle (m204)
    int nwg = gridDim.x, orig = blockIdx.x;
    int qq = nwg >> 3, rr8 = nwg & 7, xcd = orig & 7, idx = orig >> 3;
    int wgid = (xcd < rr8 ? xcd * (qq + 1) : rr8 * (qq + 1) + (xcd - rr8) * qq) + idx;
    int tm = wgid / ntn, tn = wgid - tm * ntn;

    int t, row0, mrows;
    if (GROUPED) {
        if (tm >= ctrl[C_NTILES]) return;
        t = ctrl[C_TTASK + tm];
        row0 = ctrl[C_TROW + tm];
        mrows = min(128, ctrl[C_OFFS + t + 1] - row0);
    } else {
        t = 0; row0 = tm * 128; mrows = 128;
    }
    const f16* Wt = W + (long)t * wstride;
    const float* bt = bias + (long)t * bstride;
    int n0 = tn * 64;

    // staging: thread g covers (row g>>3 in a 32-row chunk, LDS slot g&7);
    // global 16B-chunk = (g&7) ^ (row&7)  (inverse swizzle).
    int rowc = tid >> 3;   // 0..31
    long srcElem = (long)rowc * K + (((tid & 7) ^ (rowc & 7)) << 3);
    int dstOff = wave << 10;   // wave-uniform; HW adds lane*16
    const f16* Abase = A + (long)row0 * K + srcElem;
    const f16* Bbase = Wt + (long)n0 * K + srcElem;

    f32x4 acc[4][2];
#pragma unroll
    for (int i = 0; i < 4; ++i)
#pragma unroll
        for (int j = 0; j < 2; ++j) acc[i][j] = (f32x4){0.f, 0.f, 0.f, 0.f};

    // read addressing: byte = row*128 + (slot^(lane&7))*16, slot = ks*4+(lane>>4)
    int slot0 = ((lane >> 4) ^ (lane & 7)) << 4;
    const char* aptr = lds + (wm * 64 + (lane & 15)) * 128 + slot0;
    const char* bptr = lds + 16384 + (wn * 32 + (lane & 15)) * 128 + slot0;

    int NI = K >> 6;
    for (int kt = 0; kt < NI; ++kt) {
        const f16* a = Abase + kt * 64;
        const f16* b = Bbase + kt * 64;
#pragma unroll
        for (int c = 0; c < 4; ++c)
            __builtin_amdgcn_global_load_lds(
                (const __attribute__((address_space(1))) unsigned int*)(a + (long)c * 32 * K),
                (__attribute__((address_space(3))) unsigned int*)(lds + c * 4096 + dstOff), 16, 0, 0);
#pragma unroll
        for (int c = 0; c < 2; ++c)
            __builtin_amdgcn_global_load_lds(
                (const __attribute__((address_space(1))) unsigned int*)(b + (long)c * 32 * K),
                (__attribute__((address_space(3))) unsigned int*)(lds + 16384 + c * 4096 + dstOff), 16, 0, 0);
        __syncthreads();

#pragma unroll
        for (int ks = 0; ks < 2; ++ks) {
            int xo = ((slot0 ^ (ks * 64)) - slot0);
            f16x8 af[4], bf[2];
#pragma unroll
            for (int mi = 0; mi < 4; ++mi)
                af[mi] = *(const f16x8*)(aptr + mi * 2048 + xo);
#pragma unroll
            for (int nj = 0; nj < 2; ++nj)
                bf[nj] = *(const f16x8*)(bptr + nj * 2048 + xo);
#pragma unroll
            for (int mi = 0; mi < 4; ++mi)
#pragma unroll
                for (int nj = 0; nj < 2; ++nj)
                    acc[mi][nj] = __builtin_amdgcn_mfma_f32_16x16x32_f16(af[mi], bf[nj], acc[mi][nj], 0, 0, 0);
        }
        __syncthreads();
    }

    // epilogue
    int cq = lane >> 4, cr = lane & 15;
#pragma unroll
    for (int mi = 0; mi < 4; ++mi) {
#pragma unroll
        for (int nj = 0; nj < 2; ++nj) {
#pragma unroll
            for (int reg = 0; reg < 4; ++reg) {
                int rl = wm * 64 + mi * 16 + cq * 4 + reg;
                if (rl >= mrows) continue;
                int gcol = n0 + wn * 32 + nj * 16 + cr;
                if (gcol >= N) continue;
                float v = acc[mi][nj][reg] + bt[gcol];
                int grow = row0 + rl;
                if (EPI == 0) {
                    outF16[(long)grow * H_ + gcol] = (f16)(v > 0.f ? v : 0.f);
                } else if (EPI == 1) {
                    int r = perm[grow];
                    if (gcol < L_) o0[(long)r * L_ + gcol] = v;
                    else o1[(long)r * L_ + (gcol - L_)] = v;
                } else {
                    o0[(long)perm[grow] * D_ + gcol] = 1.f / (1.f + __expf(-v));
                }
            }
        }
    }
}

extern "C" void kernel_launch(void* const* d_in, const int* in_sizes, int n_in,
                              void* d_out, int out_size, void* d_ws, size_t ws_size,
                              hipStream_t stream) {
    const float* x   = (const float*)d_in[0];
    const float* eps = (const float*)d_in[1];
    const float* eW1 = (const float*)d_in[2];
    const float* eb1 = (const float*)d_in[3];
    const float* eW2 = (const float*)d_in[4];
    const float* eb2 = (const float*)d_in[5];
    const float* eW3 = (const float*)d_in[6];
    const float* eb3 = (const float*)d_in[7];
    const float* dW1 = (const float*)d_in[8];
    const float* db1 = (const float*)d_in[9];
    const float* dW2 = (const float*)d_in[10];
    const float* db2 = (const float*)d_in[11];
    const float* hW  = (const float*)d_in[12];
    const float* hb  = (const float*)d_in[13];
    const int* task  = (const int*)d_in[14];

    float* out = (float*)d_out;
    float* recon = out;
    float* mu = out + (size_t)B_ * D_;
    float* ls = mu + (size_t)B_ * L_;

    char* w = (char*)d_ws;
    size_t o = 0;
    auto alloc = [&](size_t bytes) -> char* {
        char* p = w + o;
        o = (o + bytes + 255) & ~(size_t)255;
        return p;
    };
    int* ctrl  = (int*)alloc(4096);
    int* perm  = (int*)alloc((size_t)B_ * 4);
    f16* Xp    = (f16*)alloc((size_t)(B_ + PADROWS) * KP1 * 2);
    f16* H1    = (f16*)alloc((size_t)(B_ + PADROWS) * H_ * 2);
    f16* H2    = (f16*)alloc((size_t)(B_ + PADROWS) * H_ * 2);
    f16* Z     = (f16*)alloc((size_t)(B_ + PADROWS) * L_ * 2);
    f16* Wt1   = (f16*)alloc((size_t)T_ * H_ * KP1 * 2);
    f16* Wt2   = (f16*)alloc((size_t)T_ * H_ * H_ * 2);
    f16* Wt3   = (f16*)alloc((size_t)T_ * 256 * H_ * 2);
    f16* WtD1  = (f16*)alloc((size_t)H_ * L_ * 2);
    f16* WtD2  = (f16*)alloc((size_t)H_ * H_ * 2);
    f16* WtH   = (f16*)alloc((size_t)T_ * NPH * H_ * 2);
    if (o > ws_size) return;

    k_init<<<1, 64, 0, stream>>>(ctrl);
    k_count<<<B_ / 256, 256, 0, stream>>>(task, ctrl);
    k_scan<<<1, 1, 0, stream>>>(ctrl);
    k_scatter<<<B_ / 256, 256, 0, stream>>>(task, ctrl, perm);
    k_gather_x<<<B_, 256, 0, stream>>>(x, perm, Xp);

    ConvArgs ca;
    int base = 0;
    auto seg = [&](const float* s, f16* d, int K, int N, int Kp, int Np, int T) {
        ConvSeg sg; sg.src = s; sg.dst = d; sg.K = K; sg.N = N; sg.Kp = Kp; sg.Np = Np;
        sg.ntx = Kp / 64; sg.nty = Np / 64; sg.base = base;
        base += sg.ntx * sg.nty * T;
        return sg;
    };
    ca.s[0] = seg(eW1, Wt1, D_, H_, KP1, H_, T_);
    ca.s[1] = seg(eW2, Wt2, H_, H_, H_, H_, T_);
    ca.s[2] = seg(eW3, Wt3, H_, 256, H_, 256, T_);
    ca.s[3] = seg(dW1, WtD1, L_, H_, L_, H_, 1);
    ca.s[4] = seg(dW2, WtD2, H_, H_, H_, H_, 1);
    ca.s[5] = seg(hW, WtH, H_, D_, H_, NPH, T_);
    k_convAll<<<base, 256, 0, stream>>>(ca);

    int gridG = MAXTILES * 16;     // 1184 (grouped, 16 N-tiles of 64)
    int gridG3 = MAXTILES * 4;     // 296 (enc3, N=256 -> 4 N-tiles)
    int gridD = (B_ / 128) * 16;   // 1024 (dense)
    int gridH = MAXTILES * 14;     // 1036 (head, 14 N-tiles cover 784..896)

    // encoder layer 1: Xp(K=896) @ Wt1 -> relu -> H1
    k_gemmD<0, true><<<gridG, 256, 0, stream>>>(
        Xp, Wt1, (long)H_ * KP1, eb1, H_, KP1, H_, 16, H1, nullptr, nullptr, ctrl, perm);
    // encoder layer 2: H1 @ Wt2 -> relu -> H2
    k_gemmD<0, true><<<gridG, 256, 0, stream>>>(
        H1, Wt2, (long)H_ * H_, eb2, H_, H_, H_, 16, H2, nullptr, nullptr, ctrl, perm);
    // encoder layer 3: H2 @ Wt3 -> mu/ls perm-scatter
    k_gemmD<1, true><<<gridG3, 256, 0, stream>>>(
        H2, Wt3, (long)256 * H_, eb3, 256, H_, 256, 4, nullptr, mu, ls, ctrl, perm);
    // z = mu + exp(ls)*eps
    k_z<<<(B_ * L_) / 256, 256, 0, stream>>>(mu, ls, eps, perm, Z);
    // decoder layer 1: Z(K=128) @ WtD1 -> relu -> H1
    k_gemmD<0, false><<<gridD, 256, 0, stream>>>(
        Z, WtD1, 0, db1, 0, L_, H_, 16, H1, nullptr, nullptr, ctrl, perm);
    // decoder layer 2: H1 @ WtD2 -> relu -> H2
    k_gemmD<0, false><<<gridD, 256, 0, stream>>>(
        H1, WtD2, 0, db2, 0, H_, H_, 16, H2, nullptr, nullptr, ctrl, perm);
    // head: H2 @ WtH -> sigmoid -> recon (perm-scatter fp32)
    k_gemmD<2, true><<<gridH, 256, 0, stream>>>(
        H2, WtH, (long)NPH * H_, hb, D_, H_, D_, 14, nullptr, recon, nullptr, ctrl, perm);
}